// Round 9
// baseline (136.701 us; speedup 1.0000x reference)
//
#include <hip/hip_runtime.h>
#include <math.h>

// B=64, L=128, H=16, O=8
#define LQ   128
#define BQ   64
#define LL   (LQ*LQ)
#define H1   16
#define O2   8
#define TILE 16
#define REG  18          // f1 region (origin i0-1)
#define NPTS (REG*REG)   // 324
#define PCR  22          // pc region (origin i0-3)
#define PCN  (PCR*PCR)   // 484
#define PVR  20          // pavg region (origin i0-2)
#define PVN  (PVR*PVR)   // 400
#define LKR  23          // link region (origin i0-3)
#define LKN  (LKR*LKR)   // 529
#define SDR  20          // seed tile (origin i0-2)
#define SDN  (SDR*SDR)   // 400

typedef float f2 __attribute__((ext_vector_type(2)));
using bf8 = __attribute__((ext_vector_type(8))) short;   // 8 bf16 (4 VGPR)
using f4  = __attribute__((ext_vector_type(4))) float;   // MFMA C/D

__device__ __forceinline__ int wrapi(int v) { return v & (LQ - 1); }

// pack two f32 -> dword of two bf16 (truncation) : low16=bf(lo), high16=bf(hi)
__device__ __forceinline__ unsigned pack_bf(float hi, float lo) {
    return __builtin_amdgcn_perm(__float_as_uint(hi), __float_as_uint(lo),
                                 0x07060302u);
}
// round-to-nearest-even f32 -> bf16 (low 16 bits)
__device__ __forceinline__ unsigned bfrne(float f) {
    unsigned u = __float_as_uint(f);
    u += 0x7fffu + ((u >> 16) & 1u);
    return u >> 16;
}

// ws layout:
//   float2[0 .. BQ*LL)          seed (8 MB)
//   float2[BQ*LL .. BQ*LL+120)  repacked layer-1 weights W1[t][c][op]
#define WS_W1 ((size_t)BQ * LL)

// ---------------------------------------------------------------------------
__global__ __launch_bounds__(256)
void k_scan(const float* __restrict__ x,
            const float* __restrict__ c1, const float* __restrict__ fw1,
            const float* __restrict__ bw1, float* __restrict__ ws) {
    int blk = blockIdx.x;
    if (blk == BQ * 8) {
        int tid = threadIdx.x;
        if (tid < 120) {
            int t = tid / 24, r = tid - t * 24;
            int c = r >> 3, op = r & 7;
            const float* src = (t == 0) ? c1 : (t == 1) ? fw1 : (t == 2) ? bw1
                             : (t == 3) ? (fw1 + 48) : (bw1 + 48);
            float2 v = make_float2(src[(2 * op) * 3 + c], src[(2 * op + 1) * 3 + c]);
            ((float2*)ws)[WS_W1 + tid] = v;
        }
        return;
    }
    int b = blk >> 3, rq = blk & 7;
    int l = threadIdx.x & 63, w = threadIdx.x >> 6;
    const float* x0 = x + (size_t)b * 4 * LL;
    const float* x1 = x0 + LL;

    float ur0 = x0[(2 * l) * LQ],     ui0 = x1[(2 * l) * LQ];
    float ur1 = x0[(2 * l + 1) * LQ], ui1 = x1[(2 * l + 1) * LQ];
    float pr = ur0 * ur1 - ui0 * ui1;
    float pi = ur0 * ui1 + ui0 * ur1;
    for (int d = 1; d < 64; d <<= 1) {
        float qr = __shfl_up(pr, d, 64);
        float qi = __shfl_up(pi, d, 64);
        if (l >= d) {
            float nr = qr * pr - qi * pi;
            float ni = qr * pi + qi * pr;
            pr = nr; pi = ni;
        }
    }
    float er = __shfl_up(pr, 1, 64);
    float ei = __shfl_up(pi, 1, 64);
    if (l == 0) { er = 1.f; ei = 0.f; }
    float e1r = er * ur0 - ei * ui0;
    float e1i = er * ui0 + ei * ur0;

    const float* yrp = x + (size_t)(b * 4 + 2) * LL;
    const float* yip = yrp + LL;
    float4* seed4 = (float4*)ws;

    for (int k = 0; k < 4; ++k) {
        int i = rq * 16 + w * 4 + k;
        float cxr = __shfl((i & 1) ? e1r : er, i >> 1, 64);
        float cxi = __shfl((i & 1) ? e1i : ei, i >> 1, 64);
        const float* yr = yrp + (size_t)i * LQ;
        const float* yi = yip + (size_t)i * LQ;
        float vr0 = yr[2 * l],     vi0 = yi[2 * l];
        float vr1 = yr[2 * l + 1], vi1 = yi[2 * l + 1];
        float sr = vr0 * vr1 - vi0 * vi1;
        float si = vr0 * vi1 + vi0 * vr1;
        for (int d = 1; d < 64; d <<= 1) {
            float qr = __shfl_up(sr, d, 64);
            float qi = __shfl_up(si, d, 64);
            if (l >= d) {
                float nr = qr * sr - qi * si;
                float ni = qr * si + qi * sr;
                sr = nr; si = ni;
            }
        }
        float gr = __shfl_up(sr, 1, 64);
        float gi = __shfl_up(si, 1, 64);
        if (l == 0) { gr = 1.f; gi = 0.f; }
        float s0r = cxr * gr - cxi * gi;
        float s0i = cxr * gi + cxi * gr;
        float s1r = s0r * vr0 - s0i * vi0;
        float s1i = s0r * vi0 + s0i * vr0;
        seed4[((size_t)b * LL + (size_t)i * LQ) / 2 + l] =
            make_float4(s0r, -s0i, s1r, -s1i);
    }
}

// ---------------------------------------------------------------------------
__global__ __launch_bounds__(256, 4)
void k_main(const float* __restrict__ x,
            const float* __restrict__ c2, const float* __restrict__ fw2,
            const float* __restrict__ bw2, const float* __restrict__ b1,
            const float* __restrict__ b2,
            const float* __restrict__ ro, const float* __restrict__ rob,
            const float* __restrict__ ws, float* __restrict__ out) {
    __shared__ uint4 s_f1r_lo[NPTS];   // h0-7  real  (5184 B each)
    __shared__ uint4 s_f1r_hi[NPTS];   // h8-15 real
    __shared__ uint4 s_f1i_lo[NPTS];   // h0-7  imag
    __shared__ uint4 s_f1i_hi[NPTS];   // h8-15 imag  (4 x 5184 = 20736 B)
    __shared__ f2 s_ux[LKN];           // 4232 B
    __shared__ f2 s_uy[LKN];           // 4232 B
    __shared__ float s_pc[PCN];        // 1936 B
    __shared__ float s_pv[PVN];        // 1600 B
    __shared__ f2 s_sd[SDN];           // 3200 B   (total 35936 -> 4 blk/CU)
    int tid = threadIdx.x;
    int b = blockIdx.z, i0 = blockIdx.y * TILE, j0 = blockIdx.x * TILE;
    const float* x0 = x + (size_t)b * 4 * LL;
    const float* x1 = x0 + LL;
    const float* x2 = x0 + 2 * LL;
    const float* x3 = x0 + 3 * LL;
    const float2* seed = (const float2*)ws + (size_t)b * LL;
    const float2* W1 = (const float2*)ws + WS_W1;

    // uniform zero-bias fast-path flags (exact: scale==1.0 when bias==0)
    bool z1 = true;
#pragma unroll
    for (int h = 0; h < H1; ++h) z1 = z1 && (b1[h] == 0.f);
    bool z2 = true;
#pragma unroll
    for (int o = 0; o < O2; ++o) z2 = z2 && (b2[o] == 0.f);

    // ---- Phase A: stage links (23x23, origin -3) + seed (20x20, origin -2) ----
    for (int p = tid; p < LKN; p += 256) {
        int ri = p / LKR, rj = p - ri * LKR;
        int gi = wrapi(i0 - 3 + ri), gj = wrapi(j0 - 3 + rj);
        int idx = gi * LQ + gj;
        s_ux[p] = (f2){x0[idx], x1[idx]};
        s_uy[p] = (f2){x2[idx], x3[idx]};
    }
    for (int p = tid; p < SDN; p += 256) {
        int ri = p / SDR, rj = p - ri * SDR;
        int gi = wrapi(i0 - 2 + ri), gj = wrapi(j0 - 2 + rj);
        float2 s = seed[gi * LQ + gj];
        s_sd[p] = (f2){s.x, s.y};
    }
    __syncthreads();

    // ---- Phase B: pc on 22x22 (origin -3) via complex plaquette product ----
    for (int p = tid; p < PCN; p += 256) {
        int ri = p / PCR, rj = p - ri * PCR;
        int lb = ri * LKR + rj;
        f2 u1 = s_ux[lb];
        f2 u2 = s_uy[lb + LKR];
        f2 u3 = s_ux[lb + 1];
        f2 u4 = s_uy[lb];
        float ar = u1.x * u2.x - u1.y * u2.y, ai = u1.x * u2.y + u1.y * u2.x;
        float br = ar * u3.x + ai * u3.y,     bi = -ar * u3.y + ai * u3.x;
        float zr = br * u4.x + bi * u4.y,     zi = -br * u4.y + bi * u4.x;
        s_pc[p] = zr * __frsqrt_rn(fmaf(zr, zr, zi * zi) + 1e-30f);
    }
    __syncthreads();

    // ---- Phase B2: pavg on 20x20 (origin -2), reference add order ----
    for (int p = tid; p < PVN; p += 256) {
        int ri = p / PVR, rj = p - ri * PVR;
        int c = (ri + 1) * PCR + (rj + 1);
        s_pv[p] = (s_pc[c] + s_pc[c - PCR] + s_pc[c + PCR]
                 + s_pc[c - 1] + s_pc[c + 1]) * 0.2f;
    }
    __syncthreads();

    // ---- Phase C: layer1 (+modrelu) on 18x18 -> 4 bf16 sub-planes ----
#pragma unroll
    for (int pass = 0; pass < 2; ++pass) {
        int p = tid + pass * 256;
        if (pass == 1 && p >= NPTS) break;
        int ri = p / REG, rj = p - ri * REG;
        int sc = (ri + 1) * SDR + (rj + 1);   // seed center (origin -2)
        int lb = (ri + 2) * LKR + (rj + 2);   // link center (origin -3)
        int cb = (ri + 2) * PCR + (rj + 2);   // pc center   (origin -3)
        int vb = (ri + 1) * PVR + (rj + 1);   // pv center   (origin -2)

        f2 t[5]; float tc[5], tv[5];
        {
            f2 SC = s_sd[sc], SXP = s_sd[sc + SDR], SXM = s_sd[sc - SDR];
            f2 SYP = s_sd[sc + 1], SYM = s_sd[sc - 1];
            f2 lx = s_ux[lb], ly = s_uy[lb];
            f2 mx = s_ux[lb - LKR], my = s_uy[lb - 1];
            t[0] = SC;
            t[1] = (f2){lx.x * SXP.x - lx.y * SXP.y, lx.x * SXP.y + lx.y * SXP.x};
            t[2] = (f2){mx.x * SXM.x + mx.y * SXM.y, mx.x * SXM.y - mx.y * SXM.x};
            t[3] = (f2){ly.x * SYP.x - ly.y * SYP.y, ly.x * SYP.y + ly.y * SYP.x};
            t[4] = (f2){my.x * SYM.x + my.y * SYM.y, my.x * SYM.y - my.y * SYM.x};
            tc[0] = s_pc[cb];       tv[0] = s_pv[vb];
            tc[1] = s_pc[cb + PCR]; tv[1] = s_pv[vb + PVR];
            tc[2] = s_pc[cb - PCR]; tv[2] = s_pv[vb - PVR];
            tc[3] = s_pc[cb + 1];   tv[3] = s_pv[vb + 1];
            tc[4] = s_pc[cb - 1];   tv[4] = s_pv[vb - 1];
        }

        f2 accr[8], acci[8];
#pragma unroll
        for (int op = 0; op < 8; ++op) { accr[op] = (f2){0.f, 0.f}; acci[op] = (f2){0.f, 0.f}; }
#pragma unroll
        for (int q = 0; q < 5; ++q) {
            f2 tcv = (f2){tc[q], tc[q]}, tvv = (f2){tv[q], tv[q]};
            f2 trv = (f2){t[q].x, t[q].x}, tiv = (f2){t[q].y, t[q].y};
            const float2* Wq = W1 + q * 24;
#pragma unroll
            for (int op = 0; op < 8; ++op) {
                float2 w0 = Wq[op], w1 = Wq[8 + op], w2 = Wq[16 + op];
                f2 mp = (f2){w0.x, w0.y};
                mp += (f2){w1.x, w1.y} * tcv;
                mp += (f2){w2.x, w2.y} * tvv;
                accr[op] += mp * trv;
                acci[op] += mp * tiv;
            }
        }
        if (!z1) {
#pragma unroll
            for (int op = 0; op < 8; ++op) {
                f2 q2 = accr[op] * accr[op] + acci[op] * acci[op] + (f2){1e-12f, 1e-12f};
                float s0 = fmaxf(fmaf(b1[2 * op],     __frsqrt_rn(q2.x), 1.f), 0.f);
                float s1 = fmaxf(fmaf(b1[2 * op + 1], __frsqrt_rn(q2.y), 1.f), 0.f);
                f2 sv = (f2){s0, s1};
                accr[op] *= sv; acci[op] *= sv;
            }
        }
        // pack: sub-plane dword d holds (h=2d low16, h=2d+1 high16)
        uint4 rlo, rhi, ilo, ihi;
        rlo.x = pack_bf(accr[0].y, accr[0].x); rlo.y = pack_bf(accr[1].y, accr[1].x);
        rlo.z = pack_bf(accr[2].y, accr[2].x); rlo.w = pack_bf(accr[3].y, accr[3].x);
        rhi.x = pack_bf(accr[4].y, accr[4].x); rhi.y = pack_bf(accr[5].y, accr[5].x);
        rhi.z = pack_bf(accr[6].y, accr[6].x); rhi.w = pack_bf(accr[7].y, accr[7].x);
        ilo.x = pack_bf(acci[0].y, acci[0].x); ilo.y = pack_bf(acci[1].y, acci[1].x);
        ilo.z = pack_bf(acci[2].y, acci[2].x); ilo.w = pack_bf(acci[3].y, acci[3].x);
        ihi.x = pack_bf(acci[4].y, acci[4].x); ihi.y = pack_bf(acci[5].y, acci[5].x);
        ihi.z = pack_bf(acci[6].y, acci[6].x); ihi.w = pack_bf(acci[7].y, acci[7].x);
        s_f1r_lo[p] = rlo; s_f1r_hi[p] = rhi;
        s_f1i_lo[p] = ilo; s_f1i_hi[p] = ihi;
    }
    __syncthreads();

    // ---- Phase D: layer2 via tap-paired MFMA + readout ----
    // pair pq: K 0-15 = tapLo (A rows 0-7), K 16-31 = tapHi (A rows 8-15)
    // quad 0: k0-7   -> tapLo lo-half; quad 1: k8-15  -> tapLo hi-half
    // quad 2: k16-23 -> tapHi lo-half; quad 3: k24-31 -> tapHi hi-half
    int lane = tid & 63, w = tid >> 6;
    int quad = lane >> 4, nIdx = lane & 15;
    int half = quad >> 1;            // 0: lowK tap, 1: highK tap

    const float* wLo[3] = {c2, bw2, bw2 + O2 * H1};
    const float* wHi[3] = {fw2, fw2 + O2 * H1, (const float*)0};
    bf8 afr[3];
#pragma unroll
    for (int pq = 0; pq < 3; ++pq) {
        bf8 z = {0, 0, 0, 0, 0, 0, 0, 0};
        const float* wsrc = half ? wHi[pq] : wLo[pq];
        int row = half ? (nIdx - 8) : nIdx;
        bool valid = half ? (nIdx >= 8 && wsrc != 0) : (nIdx < 8);
        if (valid) {
            const float* wp = wsrc + row * H1 + (quad & 1) * 8;
            float4 wa = *(const float4*)wp;
            float4 wb = *(const float4*)(wp + 4);
            uint4 u;
            u.x = bfrne(wa.x) | (bfrne(wa.y) << 16);
            u.y = bfrne(wa.z) | (bfrne(wa.w) << 16);
            u.z = bfrne(wb.x) | (bfrne(wb.y) << 16);
            u.w = bfrne(wb.z) | (bfrne(wb.w) << 16);
            __builtin_memcpy(&z, &u, 16);
        }
        afr[pq] = z;
    }
    const uint4* rArr = (quad & 1) ? s_f1r_hi : s_f1r_lo;
    const uint4* iArr = (quad & 1) ? s_f1i_hi : s_f1i_lo;

    float4 ro_lo = *(const float4*)ro;
    float4 ro_hi = *(const float4*)(ro + 4);
    float4 b2_lo = *(const float4*)b2;
    float4 b2_hi = *(const float4*)(b2 + 4);
    float4 zf4 = make_float4(0.f, 0.f, 0.f, 0.f);
    float4 rv = (quad == 0) ? ro_lo : ((quad == 1) ? ro_hi : zf4);
    float4 bv = (quad == 0) ? b2_lo : ((quad == 1) ? b2_hi : zf4);
    float rob0 = rob[0];

    for (int g = 0; g < 4; ++g) {
        int row = w * 4 + g;
        int posc = (row + 1) * REG + (nIdx + 1);
        int lb2 = (row + 3) * LKR + (nIdx + 3);
        f2 lx = s_ux[lb2], ly = s_uy[lb2];
        f2 mx = s_ux[lb2 - LKR], my = s_uy[lb2 - 1];

        float Lr[3], Li[3];
        Lr[0] = half ? lx.x : 1.f;   Li[0] = half ? lx.y : 0.f;
        Lr[1] = half ? ly.x : mx.x;  Li[1] = half ? ly.y : -mx.y;
        Lr[2] = half ? 0.f : my.x;   Li[2] = half ? 0.f : -my.y;
        int dpl[3];
        dpl[0] = half ? REG : 0;
        dpl[1] = half ? 1 : -REG;
        dpl[2] = -1;

        f4 a2r = {0.f, 0.f, 0.f, 0.f}, a2i = {0.f, 0.f, 0.f, 0.f};
#pragma unroll
        for (int pq = 0; pq < 3; ++pq) {
            int pos = posc + dpl[pq];
            uint4 ur = rArr[pos];
            uint4 ui = iArr[pos];
            bf8 br, bi;
            __builtin_memcpy(&br, &ur, 16);
            __builtin_memcpy(&bi, &ui, 16);
            f4 zc = {0.f, 0.f, 0.f, 0.f};
            f4 sr = __builtin_amdgcn_mfma_f32_16x16x32_bf16(afr[pq], br, zc, 0, 0, 0);
            f4 si = __builtin_amdgcn_mfma_f32_16x16x32_bf16(afr[pq], bi, zc, 0, 0, 0);
            a2r += Lr[pq] * sr - Li[pq] * si;
            a2i += Lr[pq] * si + Li[pq] * sr;
        }

        // fold highK-tap rows (quads 2/3) into lowK rows (quads 0/1)
#pragma unroll
        for (int c = 0; c < 4; ++c) {
            a2r[c] += __shfl_xor(a2r[c], 32, 64);
            a2i[c] += __shfl_xor(a2i[c], 32, 64);
        }

        f4 q4 = a2r * a2r + a2i * a2i;
        float res;
        if (z2) {
            res = rv.x * q4.x + rv.y * q4.y + rv.z * q4.z + rv.w * q4.w;
        } else {
            float bvv[4] = {bv.x, bv.y, bv.z, bv.w};
            float rvv[4] = {rv.x, rv.y, rv.z, rv.w};
            res = 0.f;
#pragma unroll
            for (int r = 0; r < 4; ++r) {
                float qq = q4[r];
                float s = fmaxf(fmaf(bvv[r], __frsqrt_rn(qq + 1e-12f), 1.f), 0.f);
                res = fmaf(rvv[r], s * s * qq, res);
            }
        }
        res += __shfl_xor(res, 16, 64);
        if (quad == 0)
            out[(size_t)b * LL + (size_t)(i0 + row) * LQ + (j0 + nIdx)] = res + rob0;
    }
}

// ---------------------------------------------------------------------------
extern "C" void kernel_launch(void* const* d_in, const int* in_sizes, int n_in,
                              void* d_out, int out_size, void* d_ws, size_t ws_size,
                              hipStream_t stream) {
    const float* x   = (const float*)d_in[0];
    const float* c1  = (const float*)d_in[1];
    const float* fw1 = (const float*)d_in[2];
    const float* bw1 = (const float*)d_in[3];
    const float* b1  = (const float*)d_in[4];
    const float* c2  = (const float*)d_in[5];
    const float* fw2 = (const float*)d_in[6];
    const float* bw2 = (const float*)d_in[7];
    const float* b2  = (const float*)d_in[8];
    const float* ro  = (const float*)d_in[9];
    const float* rob = (const float*)d_in[10];
    float* out = (float*)d_out;
    float* ws  = (float*)d_ws;

    k_scan<<<BQ * 8 + 1, 256, 0, stream>>>(x, c1, fw1, bw1, ws);
    dim3 grid(LQ / TILE, LQ / TILE, BQ);
    k_main<<<grid, 256, 0, stream>>>(x, c2, fw2, bw2, b1, b2,
                                     ro, rob, ws, out);
}

// Round 10
// 136.301 us; speedup vs baseline: 1.0029x; 1.0029x over previous
//
#include <hip/hip_runtime.h>
#include <math.h>

// B=64, L=128, H=16, O=8
#define LQ   128
#define BQ   64
#define LL   (LQ*LQ)
#define H1   16
#define O2   8
#define TILE 16
#define REG  18          // f1 region (origin i0-1)
#define NPTS (REG*REG)   // 324
#define PCR  22          // pc region (origin i0-3)
#define PCN  (PCR*PCR)   // 484
#define LKR  23          // link region (origin i0-3)
#define LKN  (LKR*LKR)   // 529
#define SDR  20          // seed tile (origin i0-2)
#define SDN  (SDR*SDR)   // 400
#define FSTR 10          // f1 plane stride per point in dwords (8 data + 2 pad)

typedef float f2 __attribute__((ext_vector_type(2)));
using bf8 = __attribute__((ext_vector_type(8))) short;   // 8 bf16 (4 VGPR)
using f4  = __attribute__((ext_vector_type(4))) float;   // MFMA C/D

__device__ __forceinline__ int wrapi(int v) { return v & (LQ - 1); }

// pack two f32 -> dword of two bf16 (truncation) : low16=bf(lo), high16=bf(hi)
__device__ __forceinline__ unsigned pack_bf(float hi, float lo) {
    return __builtin_amdgcn_perm(__float_as_uint(hi), __float_as_uint(lo),
                                 0x07060302u);
}
// round-to-nearest-even f32 -> bf16 (low 16 bits)
__device__ __forceinline__ unsigned bfrne(float f) {
    unsigned u = __float_as_uint(f);
    u += 0x7fffu + ((u >> 16) & 1u);
    return u >> 16;
}

// ws layout:
//   float2[0 .. BQ*LL)          seed (8 MB)
//   float2[BQ*LL .. BQ*LL+120)  repacked layer-1 weights W1[t][c][op]
#define WS_W1 ((size_t)BQ * LL)

// ---------------------------------------------------------------------------
__global__ __launch_bounds__(256)
void k_scan(const float* __restrict__ x,
            const float* __restrict__ c1, const float* __restrict__ fw1,
            const float* __restrict__ bw1, float* __restrict__ ws) {
    int blk = blockIdx.x;
    if (blk == BQ * 8) {
        int tid = threadIdx.x;
        if (tid < 120) {
            int t = tid / 24, r = tid - t * 24;
            int c = r >> 3, op = r & 7;
            const float* src = (t == 0) ? c1 : (t == 1) ? fw1 : (t == 2) ? bw1
                             : (t == 3) ? (fw1 + 48) : (bw1 + 48);
            float2 v = make_float2(src[(2 * op) * 3 + c], src[(2 * op + 1) * 3 + c]);
            ((float2*)ws)[WS_W1 + tid] = v;
        }
        return;
    }
    int b = blk >> 3, rq = blk & 7;
    int l = threadIdx.x & 63, w = threadIdx.x >> 6;
    const float* x0 = x + (size_t)b * 4 * LL;
    const float* x1 = x0 + LL;

    float ur0 = x0[(2 * l) * LQ],     ui0 = x1[(2 * l) * LQ];
    float ur1 = x0[(2 * l + 1) * LQ], ui1 = x1[(2 * l + 1) * LQ];
    float pr = ur0 * ur1 - ui0 * ui1;
    float pi = ur0 * ui1 + ui0 * ur1;
    for (int d = 1; d < 64; d <<= 1) {
        float qr = __shfl_up(pr, d, 64);
        float qi = __shfl_up(pi, d, 64);
        if (l >= d) {
            float nr = qr * pr - qi * pi;
            float ni = qr * pi + qi * pr;
            pr = nr; pi = ni;
        }
    }
    float er = __shfl_up(pr, 1, 64);
    float ei = __shfl_up(pi, 1, 64);
    if (l == 0) { er = 1.f; ei = 0.f; }
    float e1r = er * ur0 - ei * ui0;
    float e1i = er * ui0 + ei * ur0;

    const float* yrp = x + (size_t)(b * 4 + 2) * LL;
    const float* yip = yrp + LL;
    float4* seed4 = (float4*)ws;

    for (int k = 0; k < 4; ++k) {
        int i = rq * 16 + w * 4 + k;
        float cxr = __shfl((i & 1) ? e1r : er, i >> 1, 64);
        float cxi = __shfl((i & 1) ? e1i : ei, i >> 1, 64);
        const float* yr = yrp + (size_t)i * LQ;
        const float* yi = yip + (size_t)i * LQ;
        float vr0 = yr[2 * l],     vi0 = yi[2 * l];
        float vr1 = yr[2 * l + 1], vi1 = yi[2 * l + 1];
        float sr = vr0 * vr1 - vi0 * vi1;
        float si = vr0 * vi1 + vi0 * vr1;
        for (int d = 1; d < 64; d <<= 1) {
            float qr = __shfl_up(sr, d, 64);
            float qi = __shfl_up(si, d, 64);
            if (l >= d) {
                float nr = qr * sr - qi * si;
                float ni = qr * si + qi * sr;
                sr = nr; si = ni;
            }
        }
        float gr = __shfl_up(sr, 1, 64);
        float gi = __shfl_up(si, 1, 64);
        if (l == 0) { gr = 1.f; gi = 0.f; }
        float s0r = cxr * gr - cxi * gi;
        float s0i = cxr * gi + cxi * gr;
        float s1r = s0r * vr0 - s0i * vi0;
        float s1i = s0r * vi0 + s0i * vr0;
        seed4[((size_t)b * LL + (size_t)i * LQ) / 2 + l] =
            make_float4(s0r, -s0i, s1r, -s1i);
    }
}

// ---------------------------------------------------------------------------
__global__ __launch_bounds__(256, 4)
void k_main(const float* __restrict__ x,
            const float* __restrict__ c2, const float* __restrict__ fw2,
            const float* __restrict__ bw2, const float* __restrict__ b1,
            const float* __restrict__ b2,
            const float* __restrict__ ro, const float* __restrict__ rob,
            const float* __restrict__ ws, float* __restrict__ out) {
    __shared__ unsigned s_f1r[NPTS * FSTR];  // bf16 pairs, h-major: 12960 B
    __shared__ unsigned s_f1i[NPTS * FSTR];  // 12960 B
    __shared__ f2 s_ux[LKN];                 // 4232 B
    __shared__ f2 s_uy[LKN];                 // 4232 B
    __shared__ float s_pc[PCN];              // 1936 B
    __shared__ f2 s_sd[SDN];                 // 3200 B  (total 39520 -> 4 blk/CU)
    int tid = threadIdx.x;
    int b = blockIdx.z, i0 = blockIdx.y * TILE, j0 = blockIdx.x * TILE;
    const float* x0 = x + (size_t)b * 4 * LL;
    const float* x1 = x0 + LL;
    const float* x2 = x0 + 2 * LL;
    const float* x3 = x0 + 3 * LL;
    const float2* seed = (const float2*)ws + (size_t)b * LL;
    const float2* W1 = (const float2*)ws + WS_W1;

    // uniform zero-bias fast-path flags (exact: scale==1.0 when bias==0)
    bool z1 = true;
#pragma unroll
    for (int h = 0; h < H1; ++h) z1 = z1 && (b1[h] == 0.f);
    bool z2 = true;
#pragma unroll
    for (int o = 0; o < O2; ++o) z2 = z2 && (b2[o] == 0.f);

    // ---- Phase A: stage links (23x23, origin -3) + seed (20x20, origin -2) ----
    for (int p = tid; p < LKN; p += 256) {
        int ri = p / LKR, rj = p - ri * LKR;
        int gi = wrapi(i0 - 3 + ri), gj = wrapi(j0 - 3 + rj);
        int idx = gi * LQ + gj;
        s_ux[p] = (f2){x0[idx], x1[idx]};
        s_uy[p] = (f2){x2[idx], x3[idx]};
    }
    for (int p = tid; p < SDN; p += 256) {
        int ri = p / SDR, rj = p - ri * SDR;
        int gi = wrapi(i0 - 2 + ri), gj = wrapi(j0 - 2 + rj);
        float2 s = seed[gi * LQ + gj];
        s_sd[p] = (f2){s.x, s.y};
    }
    __syncthreads();

    // ---- Phase B: pc on 22x22 (origin -3) via complex plaquette product ----
    for (int p = tid; p < PCN; p += 256) {
        int ri = p / PCR, rj = p - ri * PCR;
        int lb = ri * LKR + rj;
        f2 u1 = s_ux[lb];
        f2 u2 = s_uy[lb + LKR];
        f2 u3 = s_ux[lb + 1];
        f2 u4 = s_uy[lb];
        float ar = u1.x * u2.x - u1.y * u2.y, ai = u1.x * u2.y + u1.y * u2.x;
        float br = ar * u3.x + ai * u3.y,     bi = -ar * u3.y + ai * u3.x;
        float zr = br * u4.x + bi * u4.y,     zi = -br * u4.y + bi * u4.x;
        s_pc[p] = zr * __frsqrt_rn(fmaf(zr, zr, zi * zi) + 1e-30f);
    }
    __syncthreads();

    // ---- Phase C: layer1 (+modrelu) on 18x18 -> split bf16 h-major planes ----
#pragma unroll
    for (int pass = 0; pass < 2; ++pass) {
        int p = tid + pass * 256;
        if (pass == 1 && p >= NPTS) break;
        int ri = p / REG, rj = p - ri * REG;
        int sc = (ri + 1) * SDR + (rj + 1);
        int lb = (ri + 2) * LKR + (rj + 2);
        int cb = (ri + 2) * PCR + (rj + 2);

        f2 t[5]; float tc[5], tv[5];
        {
            f2 SC = s_sd[sc], SXP = s_sd[sc + SDR], SXM = s_sd[sc - SDR];
            f2 SYP = s_sd[sc + 1], SYM = s_sd[sc - 1];
            f2 lx = s_ux[lb], ly = s_uy[lb];
            f2 mx = s_ux[lb - LKR], my = s_uy[lb - 1];
            t[0] = SC;
            t[1] = (f2){lx.x * SXP.x - lx.y * SXP.y, lx.x * SXP.y + lx.y * SXP.x};
            t[2] = (f2){mx.x * SXM.x + mx.y * SXM.y, mx.x * SXM.y - mx.y * SXM.x};
            t[3] = (f2){ly.x * SYP.x - ly.y * SYP.y, ly.x * SYP.y + ly.y * SYP.x};
            t[4] = (f2){my.x * SYM.x + my.y * SYM.y, my.x * SYM.y - my.y * SYM.x};
            // 13-point pc diamond (dedup of 5 overlapping 5-point stencils)
            float p00 = s_pc[cb];
            float pP0 = s_pc[cb + PCR],     pM0 = s_pc[cb - PCR];
            float p0P = s_pc[cb + 1],       p0M = s_pc[cb - 1];
            float pP20 = s_pc[cb + 2*PCR],  pM20 = s_pc[cb - 2*PCR];
            float p0P2 = s_pc[cb + 2],      p0M2 = s_pc[cb - 2];
            float pPP = s_pc[cb + PCR + 1], pPM = s_pc[cb + PCR - 1];
            float pMP = s_pc[cb - PCR + 1], pMM = s_pc[cb - PCR - 1];
            tc[0] = p00; tc[1] = pP0; tc[2] = pM0; tc[3] = p0P; tc[4] = p0M;
            tv[0] = (p00 + pP0 + pM0 + p0P + p0M) * 0.2f;
            tv[1] = (pP0 + pP20 + p00 + pPP + pPM) * 0.2f;
            tv[2] = (pM0 + p00 + pM20 + pMP + pMM) * 0.2f;
            tv[3] = (p0P + pPP + pMP + p0P2 + p00) * 0.2f;
            tv[4] = (p0M + pPM + pMM + p00 + p0M2) * 0.2f;
        }

        f2 accr[8], acci[8];
#pragma unroll
        for (int op = 0; op < 8; ++op) { accr[op] = (f2){0.f, 0.f}; acci[op] = (f2){0.f, 0.f}; }
#pragma unroll
        for (int q = 0; q < 5; ++q) {
            f2 tcv = (f2){tc[q], tc[q]}, tvv = (f2){tv[q], tv[q]};
            f2 trv = (f2){t[q].x, t[q].x}, tiv = (f2){t[q].y, t[q].y};
            const float2* Wq = W1 + q * 24;
#pragma unroll
            for (int op = 0; op < 8; ++op) {
                float2 w0 = Wq[op], w1 = Wq[8 + op], w2 = Wq[16 + op];
                f2 mp = (f2){w0.x, w0.y};
                mp += (f2){w1.x, w1.y} * tcv;
                mp += (f2){w2.x, w2.y} * tvv;
                accr[op] += mp * trv;
                acci[op] += mp * tiv;
            }
        }
        if (!z1) {
#pragma unroll
            for (int op = 0; op < 8; ++op) {
                f2 q2 = accr[op] * accr[op] + acci[op] * acci[op] + (f2){1e-12f, 1e-12f};
                float s0 = fmaxf(fmaf(b1[2 * op],     __frsqrt_rn(q2.x), 1.f), 0.f);
                float s1 = fmaxf(fmaf(b1[2 * op + 1], __frsqrt_rn(q2.y), 1.f), 0.f);
                f2 sv = (f2){s0, s1};
                accr[op] *= sv; acci[op] *= sv;
            }
        }
        // pack: plane dword op holds (h=2op low16, h=2op+1 high16), v_perm trunc
        unsigned* fr_ = &s_f1r[p * FSTR];
        unsigned* fi_ = &s_f1i[p * FSTR];
#pragma unroll
        for (int d = 0; d < 4; ++d) {
            unsigned r0 = pack_bf(accr[2*d].y,   accr[2*d].x);
            unsigned r1 = pack_bf(accr[2*d+1].y, accr[2*d+1].x);
            unsigned q0 = pack_bf(acci[2*d].y,   acci[2*d].x);
            unsigned q1 = pack_bf(acci[2*d+1].y, acci[2*d+1].x);
            *(uint2*)&fr_[2*d] = make_uint2(r0, r1);
            *(uint2*)&fi_[2*d] = make_uint2(q0, q1);
        }
    }
    __syncthreads();

    // ---- Phase D: layer2 via tap-paired MFMA + readout ----
    // pair pq: K 0-15 = tapLo (A rows 0-7), K 16-31 = tapHi (A rows 8-15)
    // pairs: (center, fwd_x), (bwd_x, fwd_y), (bwd_y, -)
    int lane = tid & 63, w = tid >> 6;
    int quad = lane >> 4, nIdx = lane & 15;
    int half = quad >> 1;            // 0: lowK tap, 1: highK tap
    int koff = (quad & 1) * 4;       // dword offset within a plane's 8

    const float* wLo[3] = {c2, bw2, bw2 + O2 * H1};
    const float* wHi[3] = {fw2, fw2 + O2 * H1, (const float*)0};
    bf8 afr[3];
#pragma unroll
    for (int pq = 0; pq < 3; ++pq) {
        bf8 z = {0, 0, 0, 0, 0, 0, 0, 0};
        const float* wsrc = half ? wHi[pq] : wLo[pq];
        int row = half ? (nIdx - 8) : nIdx;
        bool valid = half ? (nIdx >= 8 && wsrc != 0) : (nIdx < 8);
        if (valid) {
            const float* wp = wsrc + row * H1 + (quad & 1) * 8;
            float4 wa = *(const float4*)wp;
            float4 wb = *(const float4*)(wp + 4);
            uint4 u;
            u.x = bfrne(wa.x) | (bfrne(wa.y) << 16);
            u.y = bfrne(wa.z) | (bfrne(wa.w) << 16);
            u.z = bfrne(wb.x) | (bfrne(wb.y) << 16);
            u.w = bfrne(wb.z) | (bfrne(wb.w) << 16);
            __builtin_memcpy(&z, &u, 16);
        }
        afr[pq] = z;
    }
    float4 ro_lo = *(const float4*)ro;
    float4 ro_hi = *(const float4*)(ro + 4);
    float4 b2_lo = *(const float4*)b2;
    float4 b2_hi = *(const float4*)(b2 + 4);
    float4 zf4 = make_float4(0.f, 0.f, 0.f, 0.f);
    float4 rv = (quad == 0) ? ro_lo : ((quad == 1) ? ro_hi : zf4);
    float4 bv = (quad == 0) ? b2_lo : ((quad == 1) ? b2_hi : zf4);
    float rob0 = rob[0];

    for (int g = 0; g < 4; ++g) {
        int row = w * 4 + g;
        int posc = (row + 1) * REG + (nIdx + 1);
        int lb2 = (row + 3) * LKR + (nIdx + 3);
        f2 lx = s_ux[lb2], ly = s_uy[lb2];
        f2 mx = s_ux[lb2 - LKR], my = s_uy[lb2 - 1];

        // per-pair per-lane link rotation (half selects lo/hi tap)
        float Lr[3], Li[3];
        Lr[0] = half ? lx.x : 1.f;   Li[0] = half ? lx.y : 0.f;
        Lr[1] = half ? ly.x : mx.x;  Li[1] = half ? ly.y : -mx.y;
        Lr[2] = half ? 0.f : my.x;   Li[2] = half ? 0.f : -my.y;
        // per-pair per-lane B tap offset
        int dpl[3];
        dpl[0] = half ? REG : 0;
        dpl[1] = half ? 1 : -REG;
        dpl[2] = -1;

        f4 a2r = {0.f, 0.f, 0.f, 0.f}, a2i = {0.f, 0.f, 0.f, 0.f};
#pragma unroll
        for (int pq = 0; pq < 3; ++pq) {
            int base = (posc + dpl[pq]) * FSTR + koff;
            uint2 rlo = *(const uint2*)&s_f1r[base];
            uint2 rhi = *(const uint2*)&s_f1r[base + 2];
            uint2 ilo = *(const uint2*)&s_f1i[base];
            uint2 ihi = *(const uint2*)&s_f1i[base + 2];
            bf8 br, bi;
            uint4 ur = {rlo.x, rlo.y, rhi.x, rhi.y};
            uint4 ui = {ilo.x, ilo.y, ihi.x, ihi.y};
            __builtin_memcpy(&br, &ur, 16);
            __builtin_memcpy(&bi, &ui, 16);
            f4 zc = {0.f, 0.f, 0.f, 0.f};
            f4 sr = __builtin_amdgcn_mfma_f32_16x16x32_bf16(afr[pq], br, zc, 0, 0, 0);
            f4 si = __builtin_amdgcn_mfma_f32_16x16x32_bf16(afr[pq], bi, zc, 0, 0, 0);
            a2r += Lr[pq] * sr - Li[pq] * si;
            a2i += Lr[pq] * si + Li[pq] * sr;
        }

        // fold highK-half rows (quads 2/3) into lowK rows (quads 0/1)
#pragma unroll
        for (int c = 0; c < 4; ++c) {
            a2r[c] += __shfl_xor(a2r[c], 32, 64);
            a2i[c] += __shfl_xor(a2i[c], 32, 64);
        }

        f4 q4 = a2r * a2r + a2i * a2i;
        float res;
        if (z2) {
            res = rv.x * q4.x + rv.y * q4.y + rv.z * q4.z + rv.w * q4.w;
        } else {
            float bvv[4] = {bv.x, bv.y, bv.z, bv.w};
            float rvv[4] = {rv.x, rv.y, rv.z, rv.w};
            res = 0.f;
#pragma unroll
            for (int r = 0; r < 4; ++r) {
                float qq = q4[r];
                float s = fmaxf(fmaf(bvv[r], __frsqrt_rn(qq + 1e-12f), 1.f), 0.f);
                res = fmaf(rvv[r], s * s * qq, res);
            }
        }
        res += __shfl_xor(res, 16, 64);
        if (quad == 0)
            out[(size_t)b * LL + (size_t)(i0 + row) * LQ + (j0 + nIdx)] = res + rob0;
    }
}

// ---------------------------------------------------------------------------
extern "C" void kernel_launch(void* const* d_in, const int* in_sizes, int n_in,
                              void* d_out, int out_size, void* d_ws, size_t ws_size,
                              hipStream_t stream) {
    const float* x   = (const float*)d_in[0];
    const float* c1  = (const float*)d_in[1];
    const float* fw1 = (const float*)d_in[2];
    const float* bw1 = (const float*)d_in[3];
    const float* b1  = (const float*)d_in[4];
    const float* c2  = (const float*)d_in[5];
    const float* fw2 = (const float*)d_in[6];
    const float* bw2 = (const float*)d_in[7];
    const float* b2  = (const float*)d_in[8];
    const float* ro  = (const float*)d_in[9];
    const float* rob = (const float*)d_in[10];
    float* out = (float*)d_out;
    float* ws  = (float*)d_ws;

    k_scan<<<BQ * 8 + 1, 256, 0, stream>>>(x, c1, fw1, bw1, ws);
    dim3 grid(LQ / TILE, LQ / TILE, BQ);
    k_main<<<grid, 256, 0, stream>>>(x, c2, fw2, bw2, b1, b2,
                                     ro, rob, ws, out);
}

// Round 11
// 135.602 us; speedup vs baseline: 1.0081x; 1.0052x over previous
//
#include <hip/hip_runtime.h>
#include <math.h>

// B=64, L=128, H=16, O=8
#define LQ   128
#define BQ   64
#define LL   (LQ*LQ)
#define H1   16
#define O2   8
#define TILE 16
#define REG  18          // f1 region (origin i0-1)
#define NPTS (REG*REG)   // 324
#define PCR  22          // pc region (origin i0-3)
#define PCN  (PCR*PCR)   // 484
#define LKR  23          // link region (origin i0-3)
#define LKN  (LKR*LKR)   // 529
#define SDR  20          // seed tile (origin i0-2)
#define SDN  (SDR*SDR)   // 400

typedef float f2 __attribute__((ext_vector_type(2)));
using bf8 = __attribute__((ext_vector_type(8))) short;   // 8 bf16 (4 VGPR)
using f4  = __attribute__((ext_vector_type(4))) float;   // MFMA C/D

__device__ __forceinline__ int wrapi(int v) { return v & (LQ - 1); }

// pack two f32 -> dword of two bf16 (truncation) : low16=bf(lo), high16=bf(hi)
__device__ __forceinline__ unsigned pack_bf(float hi, float lo) {
    return __builtin_amdgcn_perm(__float_as_uint(hi), __float_as_uint(lo),
                                 0x07060302u);
}
// round-to-nearest-even f32 -> bf16 (low 16 bits)
__device__ __forceinline__ unsigned bfrne(float f) {
    unsigned u = __float_as_uint(f);
    u += 0x7fffu + ((u >> 16) & 1u);
    return u >> 16;
}

// ws layout:
//   float2[0 .. BQ*LL)          seed (8 MB)
//   float2[BQ*LL .. BQ*LL+120)  repacked layer-1 weights W1[t][c][op]
#define WS_W1 ((size_t)BQ * LL)

// ---------------------------------------------------------------------------
__global__ __launch_bounds__(256)
void k_scan(const float* __restrict__ x,
            const float* __restrict__ c1, const float* __restrict__ fw1,
            const float* __restrict__ bw1, float* __restrict__ ws) {
    int blk = blockIdx.x;
    if (blk == BQ * 8) {
        int tid = threadIdx.x;
        if (tid < 120) {
            int t = tid / 24, r = tid - t * 24;
            int c = r >> 3, op = r & 7;
            const float* src = (t == 0) ? c1 : (t == 1) ? fw1 : (t == 2) ? bw1
                             : (t == 3) ? (fw1 + 48) : (bw1 + 48);
            float2 v = make_float2(src[(2 * op) * 3 + c], src[(2 * op + 1) * 3 + c]);
            ((float2*)ws)[WS_W1 + tid] = v;
        }
        return;
    }
    int b = blk >> 3, rq = blk & 7;
    int l = threadIdx.x & 63, w = threadIdx.x >> 6;
    const float* x0 = x + (size_t)b * 4 * LL;
    const float* x1 = x0 + LL;

    float ur0 = x0[(2 * l) * LQ],     ui0 = x1[(2 * l) * LQ];
    float ur1 = x0[(2 * l + 1) * LQ], ui1 = x1[(2 * l + 1) * LQ];
    float pr = ur0 * ur1 - ui0 * ui1;
    float pi = ur0 * ui1 + ui0 * ur1;
    for (int d = 1; d < 64; d <<= 1) {
        float qr = __shfl_up(pr, d, 64);
        float qi = __shfl_up(pi, d, 64);
        if (l >= d) {
            float nr = qr * pr - qi * pi;
            float ni = qr * pi + qi * pr;
            pr = nr; pi = ni;
        }
    }
    float er = __shfl_up(pr, 1, 64);
    float ei = __shfl_up(pi, 1, 64);
    if (l == 0) { er = 1.f; ei = 0.f; }
    float e1r = er * ur0 - ei * ui0;
    float e1i = er * ui0 + ei * ur0;

    const float* yrp = x + (size_t)(b * 4 + 2) * LL;
    const float* yip = yrp + LL;
    float4* seed4 = (float4*)ws;

    for (int k = 0; k < 4; ++k) {
        int i = rq * 16 + w * 4 + k;
        float cxr = __shfl((i & 1) ? e1r : er, i >> 1, 64);
        float cxi = __shfl((i & 1) ? e1i : ei, i >> 1, 64);
        const float* yr = yrp + (size_t)i * LQ;
        const float* yi = yip + (size_t)i * LQ;
        float vr0 = yr[2 * l],     vi0 = yi[2 * l];
        float vr1 = yr[2 * l + 1], vi1 = yi[2 * l + 1];
        float sr = vr0 * vr1 - vi0 * vi1;
        float si = vr0 * vi1 + vi0 * vr1;
        for (int d = 1; d < 64; d <<= 1) {
            float qr = __shfl_up(sr, d, 64);
            float qi = __shfl_up(si, d, 64);
            if (l >= d) {
                float nr = qr * sr - qi * si;
                float ni = qr * si + qi * sr;
                sr = nr; si = ni;
            }
        }
        float gr = __shfl_up(sr, 1, 64);
        float gi = __shfl_up(si, 1, 64);
        if (l == 0) { gr = 1.f; gi = 0.f; }
        float s0r = cxr * gr - cxi * gi;
        float s0i = cxr * gi + cxi * gr;
        float s1r = s0r * vr0 - s0i * vi0;
        float s1i = s0r * vi0 + s0i * vr0;
        seed4[((size_t)b * LL + (size_t)i * LQ) / 2 + l] =
            make_float4(s0r, -s0i, s1r, -s1i);
    }
}

// ---------------------------------------------------------------------------
__global__ __launch_bounds__(256, 5)
void k_main(const float* __restrict__ x,
            const float* __restrict__ c2, const float* __restrict__ fw2,
            const float* __restrict__ bw2, const float* __restrict__ b1,
            const float* __restrict__ b2,
            const float* __restrict__ ro, const float* __restrict__ rob,
            const float* __restrict__ ws, float* __restrict__ out) {
    __shared__ uint4 s_f1r4[NPTS * 2];   // bf16 pairs, h-major, 32 B/pt: 10368 B
    __shared__ uint4 s_f1i4[NPTS * 2];   // 10368 B
    __shared__ f2 s_ux[LKN];             // 4232 B
    __shared__ f2 s_uy[LKN];             // 4232 B
    __shared__ float s_pc[PCN];          // 1936 B
    __shared__ unsigned s_sd[SDN];       // bf16 (r|i<<16): 1600 B
                                         // total 32736 B -> 5 blk/CU
    int tid = threadIdx.x;
    int b = blockIdx.z, i0 = blockIdx.y * TILE, j0 = blockIdx.x * TILE;
    const float* x0 = x + (size_t)b * 4 * LL;
    const float* x1 = x0 + LL;
    const float* x2 = x0 + 2 * LL;
    const float* x3 = x0 + 3 * LL;
    const float2* seed = (const float2*)ws + (size_t)b * LL;
    const float2* W1 = (const float2*)ws + WS_W1;

    // uniform zero-bias fast-path flags (exact: scale==1.0 when bias==0)
    bool z1 = true;
#pragma unroll
    for (int h = 0; h < H1; ++h) z1 = z1 && (b1[h] == 0.f);
    bool z2 = true;
#pragma unroll
    for (int o = 0; o < O2; ++o) z2 = z2 && (b2[o] == 0.f);

    // ---- Phase A: stage links (23x23, origin -3) + seed bf16 (20x20, -2) ----
    for (int p = tid; p < LKN; p += 256) {
        int ri = p / LKR, rj = p - ri * LKR;
        int gi = wrapi(i0 - 3 + ri), gj = wrapi(j0 - 3 + rj);
        int idx = gi * LQ + gj;
        s_ux[p] = (f2){x0[idx], x1[idx]};
        s_uy[p] = (f2){x2[idx], x3[idx]};
    }
    for (int p = tid; p < SDN; p += 256) {
        int ri = p / SDR, rj = p - ri * SDR;
        int gi = wrapi(i0 - 2 + ri), gj = wrapi(j0 - 2 + rj);
        float2 s = seed[gi * LQ + gj];
        s_sd[p] = bfrne(s.x) | (bfrne(s.y) << 16);   // RNE pack
    }
    __syncthreads();

    // ---- Phase B: pc on 22x22 (origin -3) via complex plaquette product ----
    for (int p = tid; p < PCN; p += 256) {
        int ri = p / PCR, rj = p - ri * PCR;
        int lb = ri * LKR + rj;
        f2 u1 = s_ux[lb];
        f2 u2 = s_uy[lb + LKR];
        f2 u3 = s_ux[lb + 1];
        f2 u4 = s_uy[lb];
        float ar = u1.x * u2.x - u1.y * u2.y, ai = u1.x * u2.y + u1.y * u2.x;
        float br = ar * u3.x + ai * u3.y,     bi = -ar * u3.y + ai * u3.x;
        float zr = br * u4.x + bi * u4.y,     zi = -br * u4.y + bi * u4.x;
        s_pc[p] = zr * __frsqrt_rn(fmaf(zr, zr, zi * zi) + 1e-30f);
    }
    __syncthreads();

    // ---- Phase C: layer1 (+modrelu) on 18x18 -> split bf16 h-major planes ----
#pragma unroll
    for (int pass = 0; pass < 2; ++pass) {
        int p = tid + pass * 256;
        if (pass == 1 && p >= NPTS) break;
        int ri = p / REG, rj = p - ri * REG;
        int sc = (ri + 1) * SDR + (rj + 1);
        int lb = (ri + 2) * LKR + (rj + 2);
        int cb = (ri + 2) * PCR + (rj + 2);

        f2 t[5]; float tc[5], tv[5];
        {
            unsigned uC  = s_sd[sc],     uXP = s_sd[sc + SDR];
            unsigned uXM = s_sd[sc - SDR], uYP = s_sd[sc + 1], uYM = s_sd[sc - 1];
            f2 SC  = (f2){__uint_as_float(uC  << 16), __uint_as_float(uC  & 0xffff0000u)};
            f2 SXP = (f2){__uint_as_float(uXP << 16), __uint_as_float(uXP & 0xffff0000u)};
            f2 SXM = (f2){__uint_as_float(uXM << 16), __uint_as_float(uXM & 0xffff0000u)};
            f2 SYP = (f2){__uint_as_float(uYP << 16), __uint_as_float(uYP & 0xffff0000u)};
            f2 SYM = (f2){__uint_as_float(uYM << 16), __uint_as_float(uYM & 0xffff0000u)};
            f2 lx = s_ux[lb], ly = s_uy[lb];
            f2 mx = s_ux[lb - LKR], my = s_uy[lb - 1];
            t[0] = SC;
            t[1] = (f2){lx.x * SXP.x - lx.y * SXP.y, lx.x * SXP.y + lx.y * SXP.x};
            t[2] = (f2){mx.x * SXM.x + mx.y * SXM.y, mx.x * SXM.y - mx.y * SXM.x};
            t[3] = (f2){ly.x * SYP.x - ly.y * SYP.y, ly.x * SYP.y + ly.y * SYP.x};
            t[4] = (f2){my.x * SYM.x + my.y * SYM.y, my.x * SYM.y - my.y * SYM.x};
            // 13-point pc diamond (dedup of 5 overlapping 5-point stencils)
            float p00 = s_pc[cb];
            float pP0 = s_pc[cb + PCR],     pM0 = s_pc[cb - PCR];
            float p0P = s_pc[cb + 1],       p0M = s_pc[cb - 1];
            float pP20 = s_pc[cb + 2*PCR],  pM20 = s_pc[cb - 2*PCR];
            float p0P2 = s_pc[cb + 2],      p0M2 = s_pc[cb - 2];
            float pPP = s_pc[cb + PCR + 1], pPM = s_pc[cb + PCR - 1];
            float pMP = s_pc[cb - PCR + 1], pMM = s_pc[cb - PCR - 1];
            tc[0] = p00; tc[1] = pP0; tc[2] = pM0; tc[3] = p0P; tc[4] = p0M;
            tv[0] = (p00 + pP0 + pM0 + p0P + p0M) * 0.2f;
            tv[1] = (pP0 + pP20 + p00 + pPP + pPM) * 0.2f;
            tv[2] = (pM0 + p00 + pM20 + pMP + pMM) * 0.2f;
            tv[3] = (p0P + pPP + pMP + p0P2 + p00) * 0.2f;
            tv[4] = (p0M + pPM + pMM + p00 + p0M2) * 0.2f;
        }

        f2 accr[8], acci[8];
#pragma unroll
        for (int op = 0; op < 8; ++op) { accr[op] = (f2){0.f, 0.f}; acci[op] = (f2){0.f, 0.f}; }
#pragma unroll
        for (int q = 0; q < 5; ++q) {
            f2 tcv = (f2){tc[q], tc[q]}, tvv = (f2){tv[q], tv[q]};
            f2 trv = (f2){t[q].x, t[q].x}, tiv = (f2){t[q].y, t[q].y};
            const float2* Wq = W1 + q * 24;
#pragma unroll
            for (int op = 0; op < 8; ++op) {
                float2 w0 = Wq[op], w1 = Wq[8 + op], w2 = Wq[16 + op];
                f2 mp = (f2){w0.x, w0.y};
                mp += (f2){w1.x, w1.y} * tcv;
                mp += (f2){w2.x, w2.y} * tvv;
                accr[op] += mp * trv;
                acci[op] += mp * tiv;
            }
        }
        if (!z1) {
#pragma unroll
            for (int op = 0; op < 8; ++op) {
                f2 q2 = accr[op] * accr[op] + acci[op] * acci[op] + (f2){1e-12f, 1e-12f};
                float s0 = fmaxf(fmaf(b1[2 * op],     __frsqrt_rn(q2.x), 1.f), 0.f);
                float s1 = fmaxf(fmaf(b1[2 * op + 1], __frsqrt_rn(q2.y), 1.f), 0.f);
                f2 sv = (f2){s0, s1};
                accr[op] *= sv; acci[op] *= sv;
            }
        }
        // pack: dword op holds (h=2op low16, h=2op+1 high16); 2 b128 per plane
        uint4 ra, rb, ia, ib;
        ra.x = pack_bf(accr[0].y, accr[0].x); ra.y = pack_bf(accr[1].y, accr[1].x);
        ra.z = pack_bf(accr[2].y, accr[2].x); ra.w = pack_bf(accr[3].y, accr[3].x);
        rb.x = pack_bf(accr[4].y, accr[4].x); rb.y = pack_bf(accr[5].y, accr[5].x);
        rb.z = pack_bf(accr[6].y, accr[6].x); rb.w = pack_bf(accr[7].y, accr[7].x);
        ia.x = pack_bf(acci[0].y, acci[0].x); ia.y = pack_bf(acci[1].y, acci[1].x);
        ia.z = pack_bf(acci[2].y, acci[2].x); ia.w = pack_bf(acci[3].y, acci[3].x);
        ib.x = pack_bf(acci[4].y, acci[4].x); ib.y = pack_bf(acci[5].y, acci[5].x);
        ib.z = pack_bf(acci[6].y, acci[6].x); ib.w = pack_bf(acci[7].y, acci[7].x);
        s_f1r4[p * 2] = ra; s_f1r4[p * 2 + 1] = rb;
        s_f1i4[p * 2] = ia; s_f1i4[p * 2 + 1] = ib;
    }
    __syncthreads();

    // ---- Phase D: layer2 via tap-paired MFMA + readout ----
    // pair pq: K 0-15 = tapLo (A rows 0-7), K 16-31 = tapHi (A rows 8-15)
    // pairs: (center, fwd_x), (bwd_x, fwd_y), (bwd_y, -)
    int lane = tid & 63, w = tid >> 6;
    int quad = lane >> 4, nIdx = lane & 15;
    int half = quad >> 1;            // 0: lowK tap, 1: highK tap
    int ksel = quad & 1;             // which uint4 of the plane

    const float* wLo[3] = {c2, bw2, bw2 + O2 * H1};
    const float* wHi[3] = {fw2, fw2 + O2 * H1, (const float*)0};
    bf8 afr[3];
#pragma unroll
    for (int pq = 0; pq < 3; ++pq) {
        bf8 z = {0, 0, 0, 0, 0, 0, 0, 0};
        const float* wsrc = half ? wHi[pq] : wLo[pq];
        int row = half ? (nIdx - 8) : nIdx;
        bool valid = half ? (nIdx >= 8 && wsrc != 0) : (nIdx < 8);
        if (valid) {
            const float* wp = wsrc + row * H1 + ksel * 8;
            float4 wa = *(const float4*)wp;
            float4 wb = *(const float4*)(wp + 4);
            uint4 u;
            u.x = bfrne(wa.x) | (bfrne(wa.y) << 16);
            u.y = bfrne(wa.z) | (bfrne(wa.w) << 16);
            u.z = bfrne(wb.x) | (bfrne(wb.y) << 16);
            u.w = bfrne(wb.z) | (bfrne(wb.w) << 16);
            __builtin_memcpy(&z, &u, 16);
        }
        afr[pq] = z;
    }
    float4 ro_lo = *(const float4*)ro;
    float4 ro_hi = *(const float4*)(ro + 4);
    float4 b2_lo = *(const float4*)b2;
    float4 b2_hi = *(const float4*)(b2 + 4);
    float4 zf4 = make_float4(0.f, 0.f, 0.f, 0.f);
    float4 rv = (quad == 0) ? ro_lo : ((quad == 1) ? ro_hi : zf4);
    float4 bv = (quad == 0) ? b2_lo : ((quad == 1) ? b2_hi : zf4);
    float rob0 = rob[0];

    for (int g = 0; g < 4; ++g) {
        int row = w * 4 + g;
        int posc = (row + 1) * REG + (nIdx + 1);
        int lb2 = (row + 3) * LKR + (nIdx + 3);
        f2 lx = s_ux[lb2], ly = s_uy[lb2];
        f2 mx = s_ux[lb2 - LKR], my = s_uy[lb2 - 1];

        // per-pair per-lane link rotation (half selects lo/hi tap)
        float Lr[3], Li[3];
        Lr[0] = half ? lx.x : 1.f;   Li[0] = half ? lx.y : 0.f;
        Lr[1] = half ? ly.x : mx.x;  Li[1] = half ? ly.y : -mx.y;
        Lr[2] = half ? 0.f : my.x;   Li[2] = half ? 0.f : -my.y;
        // per-pair per-lane B tap offset
        int dpl[3];
        dpl[0] = half ? REG : 0;
        dpl[1] = half ? 1 : -REG;
        dpl[2] = -1;

        f4 a2r = {0.f, 0.f, 0.f, 0.f}, a2i = {0.f, 0.f, 0.f, 0.f};
#pragma unroll
        for (int pq = 0; pq < 3; ++pq) {
            int bidx = (posc + dpl[pq]) * 2 + ksel;
            uint4 ur = s_f1r4[bidx];            // one ds_read_b128
            uint4 ui = s_f1i4[bidx];            // one ds_read_b128
            bf8 br, bi;
            __builtin_memcpy(&br, &ur, 16);
            __builtin_memcpy(&bi, &ui, 16);
            f4 zc = {0.f, 0.f, 0.f, 0.f};
            f4 sr = __builtin_amdgcn_mfma_f32_16x16x32_bf16(afr[pq], br, zc, 0, 0, 0);
            f4 si = __builtin_amdgcn_mfma_f32_16x16x32_bf16(afr[pq], bi, zc, 0, 0, 0);
            a2r += Lr[pq] * sr - Li[pq] * si;
            a2i += Lr[pq] * si + Li[pq] * sr;
        }

        // fold highK-half rows (quads 2/3) into lowK rows (quads 0/1)
#pragma unroll
        for (int c = 0; c < 4; ++c) {
            a2r[c] += __shfl_xor(a2r[c], 32, 64);
            a2i[c] += __shfl_xor(a2i[c], 32, 64);
        }

        f4 q4 = a2r * a2r + a2i * a2i;
        float res;
        if (z2) {
            res = rv.x * q4.x + rv.y * q4.y + rv.z * q4.z + rv.w * q4.w;
        } else {
            float bvv[4] = {bv.x, bv.y, bv.z, bv.w};
            float rvv[4] = {rv.x, rv.y, rv.z, rv.w};
            res = 0.f;
#pragma unroll
            for (int r = 0; r < 4; ++r) {
                float qq = q4[r];
                float s = fmaxf(fmaf(bvv[r], __frsqrt_rn(qq + 1e-12f), 1.f), 0.f);
                res = fmaf(rvv[r], s * s * qq, res);
            }
        }
        res += __shfl_xor(res, 16, 64);
        if (quad == 0)
            out[(size_t)b * LL + (size_t)(i0 + row) * LQ + (j0 + nIdx)] = res + rob0;
    }
}

// ---------------------------------------------------------------------------
extern "C" void kernel_launch(void* const* d_in, const int* in_sizes, int n_in,
                              void* d_out, int out_size, void* d_ws, size_t ws_size,
                              hipStream_t stream) {
    const float* x   = (const float*)d_in[0];
    const float* c1  = (const float*)d_in[1];
    const float* fw1 = (const float*)d_in[2];
    const float* bw1 = (const float*)d_in[3];
    const float* b1  = (const float*)d_in[4];
    const float* c2  = (const float*)d_in[5];
    const float* fw2 = (const float*)d_in[6];
    const float* bw2 = (const float*)d_in[7];
    const float* b2  = (const float*)d_in[8];
    const float* ro  = (const float*)d_in[9];
    const float* rob = (const float*)d_in[10];
    float* out = (float*)d_out;
    float* ws  = (float*)d_ws;

    k_scan<<<BQ * 8 + 1, 256, 0, stream>>>(x, c1, fw1, bw1, ws);
    dim3 grid(LQ / TILE, LQ / TILE, BQ);
    k_main<<<grid, 256, 0, stream>>>(x, c2, fw2, bw2, b1, b2,
                                     ro, rob, ws, out);
}